// Round 5
// baseline (506.701 us; speedup 1.0000x reference)
//
#include <hip/hip_runtime.h>
#include <stdint.h>

#define T_SEQ 2048
#define D_MODEL 2048
#define N_KV 4
#define HD 128
#define QKV_W 3072   // fused row width: 2048 q | 512 k | 512 v

typedef unsigned short us;
typedef __attribute__((ext_vector_type(8))) short bf16x8;
typedef __attribute__((ext_vector_type(4))) float f32x4;
typedef __attribute__((ext_vector_type(8))) unsigned short u16x8;

__device__ __forceinline__ us f2bf(float f) {
  union { float f; unsigned int u; } v; v.f = f;
  unsigned int r = v.u + 0x7FFFu + ((v.u >> 16) & 1u);
  return (us)(r >> 16);
}
__device__ __forceinline__ float bf2f(us h) {
  union { unsigned int u; float f; } v; v.u = ((unsigned int)h) << 16;
  return v.f;
}

__device__ __forceinline__ void load_lds16(const void* g, void* l) {
  __builtin_amdgcn_global_load_lds(
      (const __attribute__((address_space(1))) void*)g,
      (__attribute__((address_space(3))) void*)l, 16, 0, 0);
}

__global__ void fill_diag(float* __restrict__ out, float val, int n) {
  int i = blockIdx.x * blockDim.x + threadIdx.x;
  if (i < n) out[i] = val;
}

// ---------------------------------------------------------------------------
__global__ void cast_f32_bf16(const float* __restrict__ src,
                              us* __restrict__ dst, int n8) {
  int i = blockIdx.x * blockDim.x + threadIdx.x;
  if (i >= n8) return;
  const float4* s = (const float4*)src + (size_t)i * 2;
  float4 a = s[0], b = s[1];
  u16x8 o;
  o[0] = f2bf(a.x); o[1] = f2bf(a.y); o[2] = f2bf(a.z); o[3] = f2bf(a.w);
  o[4] = f2bf(b.x); o[5] = f2bf(b.y); o[6] = f2bf(b.z); o[7] = f2bf(b.w);
  *((u16x8*)dst + i) = o;
}

// ---------------------------------------------------------------------------
// C[M][N] = A[M][K] * B[N][K]^T, bf16 in, bf16/fp32 out. m97 structure.
// ---------------------------------------------------------------------------
template <typename OUT>
__global__ __launch_bounds__(256) void gemm_bt(
    const us* __restrict__ A, const us* __restrict__ B,
    OUT* __restrict__ C, int M, int N, int K) {
  __shared__ us As[128 * 32];
  __shared__ us Bs[128 * 32];

  const int tid  = threadIdx.x;
  const int lane = tid & 63;
  const int wave = tid >> 6;
  const int l15  = lane & 15;
  const int quad = lane >> 4;
  const int bm = blockIdx.x * 128;
  const int bn = blockIdx.y * 128;
  const int wm = (wave & 1) * 64;
  const int wn = (wave >> 1) * 64;

  f32x4 acc[4][4];
#pragma unroll
  for (int i = 0; i < 4; i++)
#pragma unroll
    for (int j = 0; j < 4; j++) acc[i][j] = (f32x4)0.f;

  const int srow = tid >> 2;
  const int scol = (tid & 3) * 8;
  const us* Ag = A + (size_t)(bm + srow) * K + scol;
  const us* Bg = B + (size_t)(bn + srow) * K + scol;
  us* AsW = &As[tid * 8];
  us* BsW = &Bs[tid * 8];
  const size_t rowskip = (size_t)64 * K;

  for (int k0 = 0; k0 < K; k0 += 32) {
    load_lds16(Ag, AsW);
    load_lds16(Ag + rowskip, AsW + 2048);
    load_lds16(Bg, BsW);
    load_lds16(Bg + rowskip, BsW + 2048);
    Ag += 32; Bg += 32;
    __syncthreads();

    bf16x8 a[4], b[4];
#pragma unroll
    for (int mt = 0; mt < 4; mt++)
      a[mt] = *(const bf16x8*)&As[(wm + mt * 16 + l15) * 32 + quad * 8];
#pragma unroll
    for (int nt = 0; nt < 4; nt++)
      b[nt] = *(const bf16x8*)&Bs[(wn + nt * 16 + l15) * 32 + quad * 8];
#pragma unroll
    for (int mt = 0; mt < 4; mt++)
#pragma unroll
      for (int nt = 0; nt < 4; nt++)
        acc[mt][nt] = __builtin_amdgcn_mfma_f32_16x16x32_bf16(a[mt], b[nt], acc[mt][nt], 0, 0, 0);
    __syncthreads();
  }

#pragma unroll
  for (int mt = 0; mt < 4; mt++) {
    int row = bm + wm + mt * 16 + quad * 4;
#pragma unroll
    for (int nt = 0; nt < 4; nt++) {
      int col = bn + wn + nt * 16 + l15;
#pragma unroll
      for (int r = 0; r < 4; r++) {
        if constexpr (sizeof(OUT) == 4)
          C[(size_t)(row + r) * N + col] = acc[mt][nt][r];
        else
          C[(size_t)(row + r) * N + col] = f2bf(acc[mt][nt][r]);
      }
    }
  }
}

// ---------------------------------------------------------------------------
// RoPE in-place on fused qkv [B*T][3072]: q heads at col h*128, k heads at
// col 2048 + hk*128. angle = t * 10000^(-i/64); pairs (i, i+64).
// ---------------------------------------------------------------------------
__global__ void rope_kernel(us* __restrict__ qkv) {
  const int row = blockIdx.x;
  const int t = row & (T_SEQ - 1);
  const int tid = threadIdx.x;
  const float L2_10K_64 = 13.287712379549449f / 64.f;
  us* rp = qkv + (size_t)row * QKV_W;

#pragma unroll
  for (int it = 0; it < 4; it++) {     // 16 q heads * 64 pairs
    int idx = it * 256 + tid;
    int h = idx >> 6, i = idx & 63;
    int base = h * HD;
    float ang = (float)t * exp2f(-(float)i * L2_10K_64);
    float s, c; sincosf(ang, &s, &c);
    float x1 = bf2f(rp[base + i]);
    float x2 = bf2f(rp[base + i + 64]);
    rp[base + i]      = f2bf(x1 * c - x2 * s);
    rp[base + i + 64] = f2bf(x2 * c + x1 * s);
  }
  {                                    // 4 k heads * 64 pairs
    int h = tid >> 6, i = tid & 63;
    int base = 2048 + h * HD;
    float ang = (float)t * exp2f(-(float)i * L2_10K_64);
    float s, c; sincosf(ang, &s, &c);
    float x1 = bf2f(rp[base + i]);
    float x2 = bf2f(rp[base + i + 64]);
    rp[base + i]      = f2bf(x1 * c - x2 * s);
    rp[base + i + 64] = f2bf(x2 * c + x1 * s);
  }
}

// ---------------------------------------------------------------------------
// Causal flash attention, GQA. R0's PROVEN structure (block = pair of tiles
// {31-p, p}, single-buffer, 2 barriers/chunk) with the K-chunk widened to
// 128 keys: fixed per-chunk overhead (barrier rendezvous, softmax shfl chain,
// staging serial region, Pl RAW) now amortizes over 2x keys. 17 uniform
// chunks/block (vs 33). Kept exact-math wins: deferred l-reduce (epilogue),
// base-2 softmax. LDS 77.8KB -> 2 blocks/CU (grid 512 limits to 2 anyway).
// Plain __launch_bounds__(256): min-waves variants spilled (R1: 392MB,
// R2: 130MB scratch). Cross-round invariant to beat: 6400 cyc / wave-chunk64.
// ---------------------------------------------------------------------------
__device__ __forceinline__ int vperm(int d) { return ((d >> 3) ^ d) & 7; }

__global__ __launch_bounds__(256) void attn_kernel(
    const us* __restrict__ qkv, us* __restrict__ y) {
  __shared__ us Ks[128][136];    // 128 keys x 128 d + 8 pad; rows 272B
  __shared__ us Vt[128][128];    // V^T: [d][key], XOR-swizzled 8-key blocks
  __shared__ us Pl[4][2][16][40]; // per-wave P, one 32-key stripe (alt halves)

  const int tid  = threadIdx.x;
  const int lane = tid & 63;
  const int wave = tid >> 6;
  const int l15  = lane & 15;
  const int quad = lane >> 4;
  const int p  = blockIdx.x;           // 0..15 -> tiles {31-p, p}
  const int bh = blockIdx.y;
  const int b  = bh >> 4;
  const int h  = bh & 15;
  const int hk = h >> 2;

  const us* base = qkv + (size_t)b * T_SEQ * QKV_W;
  const int kcol = 2048 + hk * HD;
  const int vcol = kcol + 512;
  const int skey = tid >> 4;           // 0..15
  const int skk  = (tid & 15) * 8;     // 0..120
  // scale * log2(e): softmax computed in base 2 (invariant)
  const float scale = 0.12751744f;     // 1/sqrt(128) * 1.4426950408889634

  for (int half = 0; half < 2; half++) {
    const int x  = half ? p : 31 - p;  // long tile first
    const int m0 = x * 64;
    const int NC = (x + 2) >> 1;       // 128-key chunks covering keys 0..m0+63

    bf16x8 qf[4];
    {
      const us* Qrow = base + (size_t)(m0 + wave * 16 + l15) * QKV_W + h * HD;
#pragma unroll
      for (int s = 0; s < 4; s++)
        qf[s] = *(const bf16x8*)&Qrow[s * 32 + quad * 8];
    }

    f32x4 O[8];
#pragma unroll
    for (int i = 0; i < 8; i++) O[i] = (f32x4)0.f;
    float mrun[4], lrun[4];
#pragma unroll
    for (int r = 0; r < 4; r++) { mrun[r] = -INFINITY; lrun[r] = 0.f; }

    // prefetch chunk 0 (128 keys: 8 key-rows per thread)
    uint4 kreg[8]; u16x8 vreg[8];
#pragma unroll
    for (int r = 0; r < 8; r++) {
      const us* row = base + (size_t)(skey + r * 16) * QKV_W;
      kreg[r] = *(const uint4*)(row + kcol + skk);
      vreg[r] = *(const u16x8*)(row + vcol + skk);
    }

    for (int jj = 0; jj < NC; jj++) {
      const int k0 = jj * 128;
      __syncthreads();                 // prior chunk's LDS reads done
#pragma unroll
      for (int r = 0; r < 8; r++) {
        int key = skey + r * 16;
        *(uint4*)&Ks[key][skk] = kreg[r];
#pragma unroll
        for (int i = 0; i < 8; i++) {
          int d = skk + i;
          Vt[d][key ^ (vperm(d) << 3)] = vreg[r][i];
        }
      }
      __syncthreads();                 // staging visible

      if (jj + 1 < NC) {               // prefetch next chunk (hidden by compute)
        const int k0n = (jj + 1) * 128;
#pragma unroll
        for (int r = 0; r < 8; r++) {
          const us* row = base + (size_t)(k0n + skey + r * 16) * QKV_W;
          kreg[r] = *(const uint4*)(row + kcol + skk);
          vreg[r] = *(const u16x8*)(row + vcol + skk);
        }
      }

      // S = Q K^T (8 key-tiles of 16)
      f32x4 S[8];
      __builtin_amdgcn_s_setprio(1);
#pragma unroll
      for (int nt = 0; nt < 8; nt++) {
        f32x4 sa = (f32x4)0.f;
#pragma unroll
        for (int ks = 0; ks < 4; ks++) {
          bf16x8 kf = *(const bf16x8*)&Ks[nt * 16 + l15][ks * 32 + quad * 8];
          sa = __builtin_amdgcn_mfma_f32_16x16x32_bf16(qf[ks], kf, sa, 0, 0, 0);
        }
        S[nt] = sa;
      }
      __builtin_amdgcn_s_setprio(0);

      const int row0 = m0 + wave * 16 + quad * 4;
      if (jj == NC - 1) {              // diagonal chunk: mask cols > row
#pragma unroll
        for (int nt = 0; nt < 8; nt++) {
          int col = k0 + nt * 16 + l15;
#pragma unroll
          for (int r = 0; r < 4; r++) {
            float v = S[nt][r] * scale;
            if (col > row0 + r) v = -INFINITY;
            S[nt][r] = v;
          }
        }
      } else {
#pragma unroll
        for (int nt = 0; nt < 8; nt++)
#pragma unroll
          for (int r = 0; r < 4; r++) S[nt][r] *= scale;
      }

      // online softmax (base 2), ONE round per 128 keys. lrun stays a
      // per-lane partial (alpha uniform per 16-lane row group); cross-lane
      // sum deferred to epilogue.
      float pr[8][4];
#pragma unroll
      for (int r = 0; r < 4; r++) {
        float mx = fmaxf(fmaxf(fmaxf(S[0][r], S[1][r]), fmaxf(S[2][r], S[3][r])),
                         fmaxf(fmaxf(S[4][r], S[5][r]), fmaxf(S[6][r], S[7][r])));
#pragma unroll
        for (int off = 1; off < 16; off <<= 1)
          mx = fmaxf(mx, __shfl_xor(mx, off, 64));
        float mnew = fmaxf(mrun[r], mx);
        float alpha = exp2f(mrun[r] - mnew);
        mrun[r] = mnew;
        float sum = 0.f;
#pragma unroll
        for (int nt = 0; nt < 8; nt++) {
          float pv = exp2f(S[nt][r] - mnew);
          pr[nt][r] = pv;
          sum += pv;
        }
        lrun[r] = lrun[r] * alpha + sum;
#pragma unroll
        for (int ot = 0; ot < 8; ot++) O[ot][r] *= alpha;
      }

      // O += P V in four 32-key stripes; Pl alternates between 2 regions
      // (same-wave LDS is program-ordered -> correct; alternation kills the
      // WAR round-trip stall between consecutive stripes).
#pragma unroll
      for (int kh = 0; kh < 4; kh++) {
#pragma unroll
        for (int nt = 0; nt < 2; nt++)
#pragma unroll
          for (int r = 0; r < 4; r++)
            Pl[wave][kh & 1][quad * 4 + r][nt * 16 + l15] = f2bf(pr[kh * 2 + nt][r]);
        bf16x8 pf = *(const bf16x8*)&Pl[wave][kh & 1][l15][quad * 8];
        __builtin_amdgcn_s_setprio(1);
#pragma unroll
        for (int ot = 0; ot < 8; ot++) {
          int dcol = ot * 16 + l15;
          bf16x8 vf = *(const bf16x8*)&Vt[dcol][(kh * 32 + quad * 8) ^ (vperm(dcol) << 3)];
          O[ot] = __builtin_amdgcn_mfma_f32_16x16x32_bf16(pf, vf, O[ot], 0, 0, 0);
        }
        __builtin_amdgcn_s_setprio(0);
      }
    }

    // epilogue: finish the deferred cross-lane l reduction, then write
    const int t_out = m0 + wave * 16 + quad * 4;
#pragma unroll
    for (int r = 0; r < 4; r++) {
      float s = lrun[r];
#pragma unroll
      for (int off = 1; off < 16; off <<= 1)
        s += __shfl_xor(s, off, 64);
      float inv_l = 1.f / s;
      us* yrow = y + (size_t)(b * T_SEQ + t_out + r) * D_MODEL + h * HD;
#pragma unroll
      for (int ot = 0; ot < 8; ot++)
        yrow[ot * 16 + l15] = f2bf(O[ot][r] * inv_l);
    }
  }
}

// ---------------------------------------------------------------------------
extern "C" void kernel_launch(void* const* d_in, const int* in_sizes, int n_in,
                              void* d_out, int out_size, void* d_ws, size_t ws_size,
                              hipStream_t stream) {
  const float* x     = (const float*)d_in[0];  // [2,2048,2048] fp32
  const float* Wq    = (const float*)d_in[1];  // [2048,2048]
  const float* Wkv   = (const float*)d_in[2];  // [1024,2048]
  const float* Wproj = (const float*)d_in[3];  // [2048,2048]
  float* out = (float*)d_out;                  // [2,2048,2048] fp32

  const size_t NX  = (size_t)4096 * 2048;
  const size_t NWQ = (size_t)2048 * 2048;
  const size_t NWK = (size_t)1024 * 2048;
  // ws (bf16): xb | Wqkvb (3072x2048) | Wpb | ybuf  = 54.6 MB
  const size_t needed_ws = (NX + (NWQ + NWK) + NWQ + NX) * sizeof(us);

  int b0 = (n_in >= 1 && (size_t)in_sizes[0] == NX);
  int b1 = (n_in >= 2 && (size_t)in_sizes[1] == NWQ);
  int b2 = (n_in >= 3 && (size_t)in_sizes[2] == NWK);
  int b3 = (n_in >= 4 && (size_t)in_sizes[3] == NWQ);
  int ws_ok = (ws_size >= needed_ws);
  int out_ok = ((size_t)out_size == NX);
  if (!(n_in == 4 && b0 && b1 && b2 && b3 && ws_ok && out_ok)) {
    float code = 1.0e6f * (float)(n_in < 10 ? n_in : 9)
               + 1.0e5f * b0 + 1.0e4f * b1 + 1.0e3f * b2 + 1.0e2f * b3
               + 10.0f * ws_ok + 40.0f * out_ok;
    fill_diag<<<dim3((out_size + 255) / 256), dim3(256), 0, stream>>>(out, code, out_size);
    return;
  }

  us* xb     = (us*)d_ws;
  us* Wqkvb  = xb + NX;            // [3072][2048]: rows 0-2047 Wq, 2048-3071 Wkv
  us* Wpb    = Wqkvb + NWQ + NWK;
  us* ybuf   = Wpb + NWQ;
  us* qkvbuf = (us*)d_out;         // [4096][3072] bf16 parks in d_out (25.2 of 33.6 MB);
                                   // dead before proj GEMM overwrites out with fp32.

  dim3 blk(256);
  cast_f32_bf16<<<dim3((int)(NX  / 8 / 256)), blk, 0, stream>>>(x,     xb,          (int)(NX  / 8));
  cast_f32_bf16<<<dim3((int)(NWQ / 8 / 256)), blk, 0, stream>>>(Wq,    Wqkvb,       (int)(NWQ / 8));
  cast_f32_bf16<<<dim3((int)(NWK / 8 / 256)), blk, 0, stream>>>(Wkv,   Wqkvb + NWQ, (int)(NWK / 8));
  cast_f32_bf16<<<dim3((int)(NWQ / 8 / 256)), blk, 0, stream>>>(Wproj, Wpb,         (int)(NWQ / 8));

  gemm_bt<us><<<dim3(32, 24), blk, 0, stream>>>(xb, Wqkvb, qkvbuf, 4096, 3072, 2048);
  rope_kernel<<<dim3(4096), blk, 0, stream>>>(qkvbuf);
  attn_kernel<<<dim3(16, 32), blk, 0, stream>>>(qkvbuf, ybuf);
  gemm_bt<float><<<dim3(32, 16), blk, 0, stream>>>(ybuf, Wpb, out, 4096, 2048, 2048);
}

// Round 7
// 412.737 us; speedup vs baseline: 1.2277x; 1.2277x over previous
//
#include <hip/hip_runtime.h>
#include <stdint.h>

#define T_SEQ 2048
#define D_MODEL 2048
#define N_KV 4
#define HD 128
#define QKV_W 3072   // fused row width: 2048 q | 512 k | 512 v

typedef unsigned short us;
typedef __attribute__((ext_vector_type(8))) short bf16x8;
typedef __attribute__((ext_vector_type(4))) float f32x4;
typedef __attribute__((ext_vector_type(8))) unsigned short u16x8;

__device__ __forceinline__ us f2bf(float f) {
  union { float f; unsigned int u; } v; v.f = f;
  unsigned int r = v.u + 0x7FFFu + ((v.u >> 16) & 1u);
  return (us)(r >> 16);
}
__device__ __forceinline__ float bf2f(us h) {
  union { unsigned int u; float f; } v; v.u = ((unsigned int)h) << 16;
  return v.f;
}

__device__ __forceinline__ void load_lds16(const void* g, void* l) {
  __builtin_amdgcn_global_load_lds(
      (const __attribute__((address_space(1))) void*)g,
      (__attribute__((address_space(3))) void*)l, 16, 0, 0);
}

__global__ void fill_diag(float* __restrict__ out, float val, int n) {
  int i = blockIdx.x * blockDim.x + threadIdx.x;
  if (i < n) out[i] = val;
}

// ---------------------------------------------------------------------------
__global__ void cast_f32_bf16(const float* __restrict__ src,
                              us* __restrict__ dst, int n8) {
  int i = blockIdx.x * blockDim.x + threadIdx.x;
  if (i >= n8) return;
  const float4* s = (const float4*)src + (size_t)i * 2;
  float4 a = s[0], b = s[1];
  u16x8 o;
  o[0] = f2bf(a.x); o[1] = f2bf(a.y); o[2] = f2bf(a.z); o[3] = f2bf(a.w);
  o[4] = f2bf(b.x); o[5] = f2bf(b.y); o[6] = f2bf(b.z); o[7] = f2bf(b.w);
  *((u16x8*)dst + i) = o;
}

// ---------------------------------------------------------------------------
// C[M][N] = A[M][K] * B[N][K]^T, bf16 in, bf16/fp32 out.
// T3-minimum 2-phase: double-buffered LDS, stage(t+1) issued BEFORE
// compute(t), ONE barrier per K-step (its implicit vmcnt(0) drain completes
// the staged buffer; lgkmcnt(0) drain protects the buffer being overwritten).
// Previous version had stage -> barrier -> compute (zero overlap).
// LDS 32KB; occupancy unchanged (VGPR-limited 3 blocks/CU).
// ---------------------------------------------------------------------------
template <typename OUT>
__global__ __launch_bounds__(256) void gemm_bt(
    const us* __restrict__ A, const us* __restrict__ B,
    OUT* __restrict__ C, int M, int N, int K) {
  __shared__ us As[2][128 * 32];
  __shared__ us Bs[2][128 * 32];

  const int tid  = threadIdx.x;
  const int lane = tid & 63;
  const int wave = tid >> 6;
  const int l15  = lane & 15;
  const int quad = lane >> 4;
  const int bm = blockIdx.x * 128;
  const int bn = blockIdx.y * 128;
  const int wm = (wave & 1) * 64;
  const int wn = (wave >> 1) * 64;

  f32x4 acc[4][4];
#pragma unroll
  for (int i = 0; i < 4; i++)
#pragma unroll
    for (int j = 0; j < 4; j++) acc[i][j] = (f32x4)0.f;

  const int srow = tid >> 2;
  const int scol = (tid & 3) * 8;
  const us* Ag = A + (size_t)(bm + srow) * K + scol;
  const us* Bg = B + (size_t)(bn + srow) * K + scol;
  const size_t rowskip = (size_t)64 * K;

  // stage K-slice [koff, koff+32) into buffer buf
#define STAGE(buf, koff)                                            \
  do {                                                              \
    load_lds16(Ag + (koff), &As[(buf)][tid * 8]);                   \
    load_lds16(Ag + (koff) + rowskip, &As[(buf)][tid * 8 + 2048]);  \
    load_lds16(Bg + (koff), &Bs[(buf)][tid * 8]);                   \
    load_lds16(Bg + (koff) + rowskip, &Bs[(buf)][tid * 8 + 2048]);  \
  } while (0)

  STAGE(0, 0);
  __syncthreads();                     // vmcnt(0) drain: buf0 ready

  int cur = 0;
  for (int k0 = 0; k0 < K; k0 += 32) {
    if (k0 + 32 < K) STAGE(cur ^ 1, k0 + 32);  // overlaps compute below

    bf16x8 a[4], b[4];
#pragma unroll
    for (int mt = 0; mt < 4; mt++)
      a[mt] = *(const bf16x8*)&As[cur][(wm + mt * 16 + l15) * 32 + quad * 8];
#pragma unroll
    for (int nt = 0; nt < 4; nt++)
      b[nt] = *(const bf16x8*)&Bs[cur][(wn + nt * 16 + l15) * 32 + quad * 8];
#pragma unroll
    for (int mt = 0; mt < 4; mt++)
#pragma unroll
      for (int nt = 0; nt < 4; nt++)
        acc[mt][nt] = __builtin_amdgcn_mfma_f32_16x16x32_bf16(a[mt], b[nt], acc[mt][nt], 0, 0, 0);

    __syncthreads();                   // drains vmcnt(0): buf cur^1 staged;
    cur ^= 1;                          // and all reads of buf cur are done
  }
#undef STAGE

#pragma unroll
  for (int mt = 0; mt < 4; mt++) {
    int row = bm + wm + mt * 16 + quad * 4;
#pragma unroll
    for (int nt = 0; nt < 4; nt++) {
      int col = bn + wn + nt * 16 + l15;
#pragma unroll
      for (int r = 0; r < 4; r++) {
        if constexpr (sizeof(OUT) == 4)
          C[(size_t)(row + r) * N + col] = acc[mt][nt][r];
        else
          C[(size_t)(row + r) * N + col] = f2bf(acc[mt][nt][r]);
      }
    }
  }
}

// ---------------------------------------------------------------------------
// RoPE in-place on fused qkv [B*T][3072]: q heads at col h*128, k heads at
// col 2048 + hk*128. angle = t * 10000^(-i/64); pairs (i, i+64).
// ---------------------------------------------------------------------------
__global__ void rope_kernel(us* __restrict__ qkv) {
  const int row = blockIdx.x;
  const int t = row & (T_SEQ - 1);
  const int tid = threadIdx.x;
  const float L2_10K_64 = 13.287712379549449f / 64.f;
  us* rp = qkv + (size_t)row * QKV_W;

#pragma unroll
  for (int it = 0; it < 4; it++) {     // 16 q heads * 64 pairs
    int idx = it * 256 + tid;
    int h = idx >> 6, i = idx & 63;
    int base = h * HD;
    float ang = (float)t * exp2f(-(float)i * L2_10K_64);
    float s, c; sincosf(ang, &s, &c);
    float x1 = bf2f(rp[base + i]);
    float x2 = bf2f(rp[base + i + 64]);
    rp[base + i]      = f2bf(x1 * c - x2 * s);
    rp[base + i + 64] = f2bf(x2 * c + x1 * s);
  }
  {                                    // 4 k heads * 64 pairs
    int h = tid >> 6, i = tid & 63;
    int base = 2048 + h * HD;
    float ang = (float)t * exp2f(-(float)i * L2_10K_64);
    float s, c; sincosf(ang, &s, &c);
    float x1 = bf2f(rp[base + i]);
    float x2 = bf2f(rp[base + i + 64]);
    rp[base + i]      = f2bf(x1 * c - x2 * s);
    rp[base + i + 64] = f2bf(x2 * c + x1 * s);
  }
}

// ---------------------------------------------------------------------------
// Causal flash attention, GQA. EXACT R0 proven structure: block = pair of
// Q-tiles {31-p, p} (uniform 33 chunks), 64-key chunks, single Ks/Vt buffer,
// 2 barriers/chunk, register prefetch of next chunk. Only exact-math tweaks
// retained from R1-R5 (all passed, all structure-free): base-2 softmax,
// deferred l-reduce (epilogue), per-kh split Pl, setprio around MFMA.
// Structural variants all regressed: 1024-block grids (R1-R3: spill or
// residency loss), 1-barrier dbuf (R4: +28us), 128-key chunks (R5: +81us).
// Plain __launch_bounds__(256); min-waves arg spills accumulators.
// ---------------------------------------------------------------------------
__device__ __forceinline__ int vperm(int d) { return ((d >> 3) ^ d) & 7; }

__global__ __launch_bounds__(256) void attn_kernel(
    const us* __restrict__ qkv, us* __restrict__ y) {
  __shared__ us Ks[64][136];     // 128 data + 8 pad: 68 dwords/row
  __shared__ us Vt[128][64];     // V^T, XOR-swizzled 8-key blocks
  __shared__ us Pl[4][2][16][40]; // per-wave, per-kh-half P staging

  const int tid  = threadIdx.x;
  const int lane = tid & 63;
  const int wave = tid >> 6;
  const int l15  = lane & 15;
  const int quad = lane >> 4;
  const int p  = blockIdx.x;           // 0..15 -> tiles {31-p, p}
  const int bh = blockIdx.y;
  const int b  = bh >> 4;
  const int h  = bh & 15;
  const int hk = h >> 2;

  const us* base = qkv + (size_t)b * T_SEQ * QKV_W;
  const int kcol = 2048 + hk * HD;
  const int vcol = kcol + 512;
  const int skey = tid >> 4;           // 0..15
  const int skk  = (tid & 15) * 8;     // 0..120
  // scale * log2(e): softmax computed in base 2 (invariant)
  const float scale = 0.12751744f;     // 1/sqrt(128) * 1.4426950408889634

  for (int half = 0; half < 2; half++) {
    const int x  = half ? p : 31 - p;  // long tile first
    const int m0 = x * 64;

    bf16x8 qf[4];
    {
      const us* Qrow = base + (size_t)(m0 + wave * 16 + l15) * QKV_W + h * HD;
#pragma unroll
      for (int s = 0; s < 4; s++)
        qf[s] = *(const bf16x8*)&Qrow[s * 32 + quad * 8];
    }

    f32x4 O[8];
#pragma unroll
    for (int i = 0; i < 8; i++) O[i] = (f32x4)0.f;
    float mrun[4], lrun[4];
#pragma unroll
    for (int r = 0; r < 4; r++) { mrun[r] = -INFINITY; lrun[r] = 0.f; }

    // prefetch chunk 0
    uint4 kreg[4]; u16x8 vreg[4];
#pragma unroll
    for (int r = 0; r < 4; r++) {
      const us* row = base + (size_t)(skey + r * 16) * QKV_W;
      kreg[r] = *(const uint4*)(row + kcol + skk);
      vreg[r] = *(const u16x8*)(row + vcol + skk);
    }

    for (int j = 0; j <= x; j++) {
      __syncthreads();                 // prior chunk's LDS reads done
#pragma unroll
      for (int r = 0; r < 4; r++) {
        int key = skey + r * 16;
        *(uint4*)&Ks[key][skk] = kreg[r];
#pragma unroll
        for (int i = 0; i < 8; i++) {
          int d = skk + i;
          Vt[d][key ^ (vperm(d) << 3)] = vreg[r][i];
        }
      }
      __syncthreads();                 // staging visible

      if (j < x) {                     // prefetch next chunk (hidden by compute)
        const int k0n = (j + 1) * 64;
#pragma unroll
        for (int r = 0; r < 4; r++) {
          const us* row = base + (size_t)(k0n + skey + r * 16) * QKV_W;
          kreg[r] = *(const uint4*)(row + kcol + skk);
          vreg[r] = *(const u16x8*)(row + vcol + skk);
        }
      }

      // S = Q K^T
      f32x4 S[4];
      __builtin_amdgcn_s_setprio(1);
#pragma unroll
      for (int nt = 0; nt < 4; nt++) {
        f32x4 sa = (f32x4)0.f;
#pragma unroll
        for (int ks = 0; ks < 4; ks++) {
          bf16x8 kf = *(const bf16x8*)&Ks[nt * 16 + l15][ks * 32 + quad * 8];
          sa = __builtin_amdgcn_mfma_f32_16x16x32_bf16(qf[ks], kf, sa, 0, 0, 0);
        }
        S[nt] = sa;
      }
      __builtin_amdgcn_s_setprio(0);

      const int row0 = m0 + wave * 16 + quad * 4;
      if (j == x) {                    // diagonal chunk only: mask
        const int k0 = j * 64;
#pragma unroll
        for (int nt = 0; nt < 4; nt++) {
          int col = k0 + nt * 16 + l15;
#pragma unroll
          for (int r = 0; r < 4; r++) {
            float v = S[nt][r] * scale;
            if (col > row0 + r) v = -INFINITY;
            S[nt][r] = v;
          }
        }
      } else {
#pragma unroll
        for (int nt = 0; nt < 4; nt++)
#pragma unroll
          for (int r = 0; r < 4; r++) S[nt][r] *= scale;
      }

      // online softmax (base 2). lrun stays a per-lane partial (alpha is
      // uniform per 16-lane row group); cross-lane sum deferred to epilogue.
      float pr[4][4];
#pragma unroll
      for (int r = 0; r < 4; r++) {
        float mx = fmaxf(fmaxf(S[0][r], S[1][r]), fmaxf(S[2][r], S[3][r]));
#pragma unroll
        for (int off = 1; off < 16; off <<= 1)
          mx = fmaxf(mx, __shfl_xor(mx, off, 64));
        float mnew = fmaxf(mrun[r], mx);
        float alpha = exp2f(mrun[r] - mnew);
        mrun[r] = mnew;
        float sum = 0.f;
#pragma unroll
        for (int nt = 0; nt < 4; nt++) {
          float pv = exp2f(S[nt][r] - mnew);
          pr[nt][r] = pv;
          sum += pv;
        }
        lrun[r] = lrun[r] * alpha + sum;
#pragma unroll
        for (int ot = 0; ot < 8; ot++) O[ot][r] *= alpha;
      }

      // O += P V in two 32-key halves; per-kh Pl regions (no WAR stall).
      // Same-wave LDS write->read is program-ordered: no barrier needed.
#pragma unroll
      for (int kh = 0; kh < 2; kh++) {
#pragma unroll
        for (int nt = 0; nt < 2; nt++)
#pragma unroll
          for (int r = 0; r < 4; r++)
            Pl[wave][kh][quad * 4 + r][nt * 16 + l15] = f2bf(pr[kh * 2 + nt][r]);
        bf16x8 pf = *(const bf16x8*)&Pl[wave][kh][l15][quad * 8];
        __builtin_amdgcn_s_setprio(1);
#pragma unroll
        for (int ot = 0; ot < 8; ot++) {
          int dcol = ot * 16 + l15;
          bf16x8 vf = *(const bf16x8*)&Vt[dcol][(kh * 32 + quad * 8) ^ (vperm(dcol) << 3)];
          O[ot] = __builtin_amdgcn_mfma_f32_16x16x32_bf16(pf, vf, O[ot], 0, 0, 0);
        }
        __builtin_amdgcn_s_setprio(0);
      }
    }

    // epilogue: finish the deferred cross-lane l reduction, then write
    const int t_out = m0 + wave * 16 + quad * 4;
#pragma unroll
    for (int r = 0; r < 4; r++) {
      float s = lrun[r];
#pragma unroll
      for (int off = 1; off < 16; off <<= 1)
        s += __shfl_xor(s, off, 64);
      float inv_l = 1.f / s;
      us* yrow = y + (size_t)(b * T_SEQ + t_out + r) * D_MODEL + h * HD;
#pragma unroll
      for (int ot = 0; ot < 8; ot++)
        yrow[ot * 16 + l15] = f2bf(O[ot][r] * inv_l);
    }
  }
}

// ---------------------------------------------------------------------------
extern "C" void kernel_launch(void* const* d_in, const int* in_sizes, int n_in,
                              void* d_out, int out_size, void* d_ws, size_t ws_size,
                              hipStream_t stream) {
  const float* x     = (const float*)d_in[0];  // [2,2048,2048] fp32
  const float* Wq    = (const float*)d_in[1];  // [2048,2048]
  const float* Wkv   = (const float*)d_in[2];  // [1024,2048]
  const float* Wproj = (const float*)d_in[3];  // [2048,2048]
  float* out = (float*)d_out;                  // [2,2048,2048] fp32

  const size_t NX  = (size_t)4096 * 2048;
  const size_t NWQ = (size_t)2048 * 2048;
  const size_t NWK = (size_t)1024 * 2048;
  // ws (bf16): xb | Wqkvb (3072x2048) | Wpb | ybuf  = 54.6 MB
  const size_t needed_ws = (NX + (NWQ + NWK) + NWQ + NX) * sizeof(us);

  int b0 = (n_in >= 1 && (size_t)in_sizes[0] == NX);
  int b1 = (n_in >= 2 && (size_t)in_sizes[1] == NWQ);
  int b2 = (n_in >= 3 && (size_t)in_sizes[2] == NWK);
  int b3 = (n_in >= 4 && (size_t)in_sizes[3] == NWQ);
  int ws_ok = (ws_size >= needed_ws);
  int out_ok = ((size_t)out_size == NX);
  if (!(n_in == 4 && b0 && b1 && b2 && b3 && ws_ok && out_ok)) {
    float code = 1.0e6f * (float)(n_in < 10 ? n_in : 9)
               + 1.0e5f * b0 + 1.0e4f * b1 + 1.0e3f * b2 + 1.0e2f * b3
               + 10.0f * ws_ok + 40.0f * out_ok;
    fill_diag<<<dim3((out_size + 255) / 256), dim3(256), 0, stream>>>(out, code, out_size);
    return;
  }

  us* xb     = (us*)d_ws;
  us* Wqkvb  = xb + NX;            // [3072][2048]: rows 0-2047 Wq, 2048-3071 Wkv
  us* Wpb    = Wqkvb + NWQ + NWK;
  us* ybuf   = Wpb + NWQ;
  us* qkvbuf = (us*)d_out;         // [4096][3072] bf16 parks in d_out (25.2 of 33.6 MB);
                                   // dead before proj GEMM overwrites out with fp32.

  dim3 blk(256);
  cast_f32_bf16<<<dim3((int)(NX  / 8 / 256)), blk, 0, stream>>>(x,     xb,          (int)(NX  / 8));
  cast_f32_bf16<<<dim3((int)(NWQ / 8 / 256)), blk, 0, stream>>>(Wq,    Wqkvb,       (int)(NWQ / 8));
  cast_f32_bf16<<<dim3((int)(NWK / 8 / 256)), blk, 0, stream>>>(Wkv,   Wqkvb + NWQ, (int)(NWK / 8));
  cast_f32_bf16<<<dim3((int)(NWQ / 8 / 256)), blk, 0, stream>>>(Wproj, Wpb,         (int)(NWQ / 8));

  gemm_bt<us><<<dim3(32, 24), blk, 0, stream>>>(xb, Wqkvb, qkvbuf, 4096, 3072, 2048);
  rope_kernel<<<dim3(4096), blk, 0, stream>>>(qkvbuf);
  attn_kernel<<<dim3(16, 32), blk, 0, stream>>>(qkvbuf, ybuf);
  gemm_bt<float><<<dim3(32, 16), blk, 0, stream>>>(ybuf, Wpb, out, 4096, 2048, 2048);
}